// Round 15
// baseline (306.522 us; speedup 1.0000x reference)
//
#include <hip/hip_runtime.h>
#include <stdint.h>
#include <math.h>

// Problem constants (DBRX FFN): B=2 S=2048 D=1024 E=8 F=2048 K=2
#define NB 2
#define NS 2048
#define ND 1024
#define NE 8
#define NF 2048
#define NTOK (NB*NS)          // 4096 tokens
#define EFD ((size_t)NE*NF*ND)
#define NROWS (2*NTOK)        // 8192 compacted (token,slot) rows

typedef short bf16x8 __attribute__((ext_vector_type(8)));
typedef float f32x4 __attribute__((ext_vector_type(4)));

__device__ __forceinline__ unsigned short f2bf(float f) {
  unsigned u = __float_as_uint(f);
  unsigned r = (u + 0x7FFFu + ((u >> 16) & 1u)) >> 16;
  return (unsigned short)r;
}
__device__ __forceinline__ float bf2f(unsigned short s) {
  return __uint_as_float(((unsigned)s) << 16);
}

__device__ __forceinline__ void async16(unsigned short* lds, const unsigned short* g) {
  __builtin_amdgcn_global_load_lds(
      (const __attribute__((address_space(1))) unsigned int*)g,
      (__attribute__((address_space(3))) unsigned int*)lds, 16, 0, 0);
}

#define VMCNT(n) asm volatile("s_waitcnt vmcnt(" #n ")" ::: "memory")
#define LGKM0    asm volatile("s_waitcnt lgkmcnt(0)" ::: "memory")
#define SBAR     __builtin_amdgcn_s_barrier()
#define SCHED0   __builtin_amdgcn_sched_barrier(0)

// ---------------- convert fp32 -> bf16 (vectorized) ----------------
__global__ void cvt_bf16(const float* __restrict__ src,
                         unsigned short* __restrict__ dst, int n4) {
  int i = blockIdx.x * blockDim.x + threadIdx.x;
  int stride = gridDim.x * blockDim.x;
  for (; i < n4; i += stride) {
    float4 v = ((const float4*)src)[i];
    ushort4 o;
    o.x = f2bf(v.x); o.y = f2bf(v.y); o.z = f2bf(v.z); o.w = f2bf(v.w);
    ((ushort4*)dst)[i] = o;
  }
}

// ---------------- transpose w2 (E,F,D) fp32 -> w2t (E,D,F) bf16 ----------------
__global__ void transpose_w2(const float* __restrict__ w2,
                             unsigned short* __restrict__ w2t) {
  __shared__ float tile[32][33];
  int e = blockIdx.z;
  int d0 = blockIdx.x * 32, f0 = blockIdx.y * 32;
  int tx = threadIdx.x, ty = threadIdx.y;
  const float* src = w2 + (size_t)e * NF * ND;
  unsigned short* dst = w2t + (size_t)e * ND * NF;
#pragma unroll
  for (int i = ty; i < 32; i += 8)
    tile[i][tx] = src[(size_t)(f0 + i) * ND + d0 + tx];
  __syncthreads();
#pragma unroll
  for (int i = ty; i < 32; i += 8)
    dst[(size_t)(d0 + i) * NF + f0 + tx] = f2bf(tile[tx][i]);
}

// ---------------- router: wave per 16 tokens, 4 lanes per token ----------------
__global__ void router_kernel(const float* __restrict__ hs,
                              const float* __restrict__ rk,
                              float* __restrict__ wout,   // [NTOK][NE]
                              float* __restrict__ tw,     // [NTOK][2]
                              int* __restrict__ choice,   // [NTOK] e0 | e1<<4
                              unsigned short* __restrict__ hsb) {
  int lane = threadIdx.x;            // 64
  int tt = lane & 15, part = lane >> 4;
  int t = blockIdx.x * 16 + tt;      // 256 blocks
  const float4* hrow = (const float4*)(hs + (size_t)t * ND) + part * 64;
  ushort4* hb4 = (ushort4*)(hsb + (size_t)t * ND) + part * 64;
  const float4* rk4 = (const float4*)rk + part * 512;
  float acc[NE];
#pragma unroll
  for (int e = 0; e < NE; ++e) acc[e] = 0.f;
#pragma unroll 4
  for (int i = 0; i < 64; ++i) {
    float4 x = hrow[i];
    ushort4 o;
    o.x = f2bf(x.x); o.y = f2bf(x.y); o.z = f2bf(x.z); o.w = f2bf(x.w);
    hb4[i] = o;
    float xs[4] = {x.x, x.y, x.z, x.w};
#pragma unroll
    for (int j = 0; j < 4; ++j) {
      float4 r0 = rk4[i * 8 + j * 2];
      float4 r1 = rk4[i * 8 + j * 2 + 1];
      acc[0] += xs[j] * r0.x; acc[1] += xs[j] * r0.y;
      acc[2] += xs[j] * r0.z; acc[3] += xs[j] * r0.w;
      acc[4] += xs[j] * r1.x; acc[5] += xs[j] * r1.y;
      acc[6] += xs[j] * r1.z; acc[7] += xs[j] * r1.w;
    }
  }
#pragma unroll
  for (int e = 0; e < NE; ++e) {
    acc[e] += __shfl_xor(acc[e], 16, 64);
    acc[e] += __shfl_xor(acc[e], 32, 64);
  }
  if (part == 0) {
    float mx = acc[0]; int i0 = 0;
#pragma unroll
    for (int e = 1; e < NE; ++e) if (acc[e] > mx) { mx = acc[e]; i0 = e; }
    float m2 = -3.4e38f; int i1 = 0;
#pragma unroll
    for (int e = 0; e < NE; ++e) if (e != i0 && acc[e] > m2) { m2 = acc[e]; i1 = e; }
    float p[NE]; float den = 0.f;
#pragma unroll
    for (int e = 0; e < NE; ++e) { p[e] = expf(acc[e] - mx); den += p[e]; }
    float inv = 1.f / den;
#pragma unroll
    for (int e = 0; e < NE; ++e) { p[e] *= inv; wout[t * NE + e] = p[e]; }
    float w0 = p[i0], w1 = p[i1];
    float s = 1.f / (w0 + w1);
    tw[t * 2 + 0] = w0 * s;
    tw[t * 2 + 1] = w1 * s;
    choice[t] = i0 | (i1 << 4);
  }
}

// ------- build lists + per-token positions + expert prefix offsets ----------
__global__ void build_lists(const int* __restrict__ choice,
                            int* __restrict__ counts,
                            int* __restrict__ off,      // [NE+1] prefix
                            int* __restrict__ list,     // [NE][NTOK] token<<1|slot
                            int* __restrict__ posn) {   // [NTOK] p0 | p1<<16
  __shared__ int lcnt[NE];
  int tid = threadIdx.x;  // 1024
  if (tid < NE) lcnt[tid] = 0;
  __syncthreads();
  int4 c4 = ((const int4*)choice)[tid];
  int cs[4] = {c4.x, c4.y, c4.z, c4.w};
#pragma unroll
  for (int j = 0; j < 4; ++j) {
    int t = tid * 4 + j;
    int e0 = cs[j] & 15, e1 = (cs[j] >> 4) & 15;
    int p0 = atomicAdd(&lcnt[e0], 1);
    list[e0 * NTOK + p0] = t << 1;
    int p1 = atomicAdd(&lcnt[e1], 1);
    list[e1 * NTOK + p1] = (t << 1) | 1;
    posn[t] = p0 | (p1 << 16);
  }
  __syncthreads();
  if (tid == 0) {
    int s = 0;
#pragma unroll
    for (int e = 0; e < NE; ++e) { counts[e] = lcnt[e]; off[e] = s; s += lcnt[e]; }
    off[NE] = s;
  }
}

// ============ 8-phase 256x256 GEMM (m201-style), FUSED / P3 ==================
// 512 thr = 8 waves (2M x 4N): wm=wid>>2, wn=wid&3. Wave tile 128x64,
// acc[8][4]. BK=64, kT=16 K-tiles, 8 outer iters (2 tiles/iter, 8 phases).
// LDS: 2 bufs x 64KB: [A.ks0 16K][A.ks1 16K][B.ks0 16K][B.ks1 16K];
// epilogue overlay xl[256][132] fp32 (135168 B total -> 1 block/CU).
// Per phase: {4 (+4 B at even phases) ds_read_b128; 2 global_load_lds (one
// half-tile); SBAR; lgkm0+sched0; setprio(1); 16 MFMA; setprio(0);
// [odd phases: counted VMCNT(8), tail 4/0]; SBAR}. Loads land 6 phases before
// their reads; overwrites target regions barrier-retired a phase earlier.
// Chunk-XOR swizzle slot^(row&3) on 64B rows (inverse on global source).
// FUSED: A gathered by list; B = [128 w1-rows; 128 v1-rows] (f-window nt*128);
//        epilogue: x2 waves (wn>=2) -> xl; x1 waves silu-combine -> hcomp.
// P3: A = hcomp sequential; B = w2t d-rows (nt*256); split-K=2 (kh);
//        epilogue: bf16 partial -> ycomp[kh].
template <int FUSED>
__global__ __launch_bounds__(512, 2) void gemm8(
    const int* __restrict__ counts, const int* __restrict__ off,
    const int* __restrict__ list,
    const unsigned short* __restrict__ A,
    const unsigned short* __restrict__ B1,
    const unsigned short* __restrict__ B2,
    unsigned short* __restrict__ H,
    unsigned short* __restrict__ Y) {
  int bid = blockIdx.x;
  int e, mt, nt, kh = 0;
  if (FUSED) { e = bid >> 7; int r = bid & 127; mt = r >> 4; nt = r & 15; }
  else       { e = bid >> 6; int r = bid & 63;  mt = r >> 3; int c = r & 7; nt = c >> 1; kh = c & 1; }
  int cnt = counts[e];
  if (mt * 256 >= cnt) return;
  int off_e = off[e];

  __shared__ char smem[135168];   // 2 x 64KB ring + epilogue overlay

  int tid = threadIdx.x;
  int wid = tid >> 6, lane = tid & 63;
  int wm = wid >> 2, wn = wid & 3;
  int l15 = lane & 15, l4 = lane >> 4;
  const int* mylist = list + e * NTOK;

  // ---- staging sources: thread covers slots tid (row tid>>2) and tid+512 ----
  const unsigned short* aS0; const unsigned short* aS1;
  const unsigned short* bS0; const unsigned short* bS1;
  {
#pragma unroll
    for (int i = 0; i < 2; ++i) {
      int slot = tid + i * 512;
      int row = slot >> 2;                       // 0..255
      int co = ((slot & 3) ^ (row & 3)) * 8;     // inverse-swizzled elem offset
      const unsigned short* ap;
      const unsigned short* bp;
      int r = mt * 256 + row;
      if (r >= cnt) r = cnt - 1;
      if (FUSED) {
        int entry = mylist[r];
        ap = A + (size_t)(entry >> 1) * ND + co;
        bp = (row < 128)
           ? B1 + (size_t)e * NF * ND + (size_t)(nt * 128 + row) * ND + co
           : B2 + (size_t)e * NF * ND + (size_t)(nt * 128 + row - 128) * ND + co;
      } else {
        ap = A + (size_t)(off_e + r) * NF + kh * 1024 + co;
        bp = B1 + (size_t)e * ND * NF + (size_t)(nt * 256 + row) * NF + kh * 1024 + co;
      }
      if (i == 0) { aS0 = ap; bS0 = bp; } else { aS1 = ap; bS1 = bp; }
    }
  }

  // ---- swizzled fragment read byte offsets (relative to region base) ----
  int offA[8], offB[4];
#pragma unroll
  for (int mi = 0; mi < 8; ++mi) {
    int row = wm * 128 + mi * 16 + l15;
    offA[mi] = row * 64 + ((l4 ^ (row & 3)) << 4);
  }
#pragma unroll
  for (int ni = 0; ni < 4; ++ni) {
    int row = wn * 64 + ni * 16 + l15;
    offB[ni] = row * 64 + ((l4 ^ (row & 3)) << 4);
  }

  f32x4 acc[8][4];
#pragma unroll
  for (int mi = 0; mi < 8; ++mi)
#pragma unroll
    for (int ni = 0; ni < 4; ++ni) {
      f32x4 z = {0.f, 0.f, 0.f, 0.f};
      acc[mi][ni] = z;
    }

  // stage one half-tile (2 loads/thread). Regions: buf*65536 + isB*32768 + ks*16384
  auto STAGE_A = [&](int buf, int ks, int tile) {
    if (tile < 16) {
      int ko = tile * 64 + ks * 32;
      unsigned short* base = (unsigned short*)(smem + buf * 65536 + ks * 16384) + tid * 8;
      async16(base, aS0 + ko);
      async16(base + 4096, aS1 + ko);
    }
  };
  auto STAGE_B = [&](int buf, int ks, int tile) {
    if (tile < 16) {
      int ko = tile * 64 + ks * 32;
      unsigned short* base = (unsigned short*)(smem + buf * 65536 + 32768 + ks * 16384) + tid * 8;
      async16(base, bS0 + ko);
      async16(base + 4096, bS1 + ko);
    }
  };

  // ---- prologue: t0 all 4 halves -> buf0; t1 ks0 halves -> buf1 ----
  STAGE_A(0, 0, 0); STAGE_B(0, 0, 0);
  STAGE_A(0, 1, 0); STAGE_B(0, 1, 0);
  STAGE_A(1, 0, 1); STAGE_B(1, 0, 1);
  VMCNT(8);     // t0.ks0 (first 4 loads) landed
  SCHED0;
  SBAR;

  bf16x8 bq0, bq1, bq2, bq3;

#define PH(Q, BUF, MIB, KS, STG, VMT) \
  { \
    const char* ab = smem + (BUF) * 65536 + (KS) * 16384; \
    const char* bb = ab + 32768; \
    bf16x8 a0 = *(const bf16x8*)(ab + offA[(MIB) + 0]); \
    bf16x8 a1 = *(const bf16x8*)(ab + offA[(MIB) + 1]); \
    bf16x8 a2 = *(const bf16x8*)(ab + offA[(MIB) + 2]); \
    bf16x8 a3 = *(const bf16x8*)(ab + offA[(MIB) + 3]); \
    if ((Q) % 2 == 0) { \
      bq0 = *(const bf16x8*)(bb + offB[0]); \
      bq1 = *(const bf16x8*)(bb + offB[1]); \
      bq2 = *(const bf16x8*)(bb + offB[2]); \
      bq3 = *(const bf16x8*)(bb + offB[3]); \
    } \
    STG; \
    SBAR; \
    LGKM0; SCHED0; \
    __builtin_amdgcn_s_setprio(1); \
    acc[(MIB)+0][0] = __builtin_amdgcn_mfma_f32_16x16x32_bf16(a0, bq0, acc[(MIB)+0][0], 0, 0, 0); \
    acc[(MIB)+0][1] = __builtin_amdgcn_mfma_f32_16x16x32_bf16(a0, bq1, acc[(MIB)+0][1], 0, 0, 0); \
    acc[(MIB)+0][2] = __builtin_amdgcn_mfma_f32_16x16x32_bf16(a0, bq2, acc[(MIB)+0][2], 0, 0, 0); \
    acc[(MIB)+0][3] = __builtin_amdgcn_mfma_f32_16x16x32_bf16(a0, bq3, acc[(MIB)+0][3], 0, 0, 0); \
    acc[(MIB)+1][0] = __builtin_amdgcn_mfma_f32_16x16x32_bf16(a1, bq0, acc[(MIB)+1][0], 0, 0, 0); \
    acc[(MIB)+1][1] = __builtin_amdgcn_mfma_f32_16x16x32_bf16(a1, bq1, acc[(MIB)+1][1], 0, 0, 0); \
    acc[(MIB)+1][2] = __builtin_amdgcn_mfma_f32_16x16x32_bf16(a1, bq2, acc[(MIB)+1][2], 0, 0, 0); \
    acc[(MIB)+1][3] = __builtin_amdgcn_mfma_f32_16x16x32_bf16(a1, bq3, acc[(MIB)+1][3], 0, 0, 0); \
    acc[(MIB)+2][0] = __builtin_amdgcn_mfma_f32_16x16x32_bf16(a2, bq0, acc[(MIB)+2][0], 0, 0, 0); \
    acc[(MIB)+2][1] = __builtin_amdgcn_mfma_f32_16x16x32_bf16(a2, bq1, acc[(MIB)+2][1], 0, 0, 0); \
    acc[(MIB)+2][2] = __builtin_amdgcn_mfma_f32_16x16x32_bf16(a2, bq2, acc[(MIB)+2][2], 0, 0, 0); \
    acc[(MIB)+2][3] = __builtin_amdgcn_mfma_f32_16x16x32_bf16(a2, bq3, acc[(MIB)+2][3], 0, 0, 0); \
    acc[(MIB)+3][0] = __builtin_amdgcn_mfma_f32_16x16x32_bf16(a3, bq0, acc[(MIB)+3][0], 0, 0, 0); \
    acc[(MIB)+3][1] = __builtin_amdgcn_mfma_f32_16x16x32_bf16(a3, bq1, acc[(MIB)+3][1], 0, 0, 0); \
    acc[(MIB)+3][2] = __builtin_amdgcn_mfma_f32_16x16x32_bf16(a3, bq2, acc[(MIB)+3][2], 0, 0, 0); \
    acc[(MIB)+3][3] = __builtin_amdgcn_mfma_f32_16x16x32_bf16(a3, bq3, acc[(MIB)+3][3], 0, 0, 0); \
    __builtin_amdgcn_s_setprio(0); \
    VMT; \
    SBAR; \
  }

  for (int j = 0; j < 8; ++j) {
    int t1 = 2 * j + 1, t2 = 2 * j + 2, t3 = 2 * j + 3;
    bool last = (j == 7);
    PH(0, 0, 0, 0, STAGE_A(1, 1, t1), {});
    PH(1, 0, 4, 0, STAGE_B(1, 1, t1), { VMCNT(8); SCHED0; });
    PH(2, 0, 0, 1, STAGE_A(0, 0, t2), {});
    PH(3, 0, 4, 1, STAGE_B(0, 0, t2), { if (last) { VMCNT(4); } else { VMCNT(8); } SCHED0; });
    PH(4, 1, 0, 0, STAGE_A(0, 1, t2), {});
    PH(5, 1, 4, 0, STAGE_B(0, 1, t2), { if (last) { VMCNT(0); } else { VMCNT(8); } SCHED0; });
    PH(6, 1, 0, 1, STAGE_A(1, 0, t3), {});
    PH(7, 1, 4, 1, STAGE_B(1, 0, t3), { if (!last) { VMCNT(8); SCHED0; } });
  }
#undef PH

  // ---- epilogue ----
  if (FUSED) {
    float* xl = (float*)smem;         // [256][132] fp32 overlay
    if (wn >= 2) {
#pragma unroll
      for (int mi = 0; mi < 8; ++mi)
#pragma unroll
        for (int jj = 0; jj < 4; ++jj) {
          int row = wm * 128 + mi * 16 + l4 * 4 + jj;
#pragma unroll
          for (int ni = 0; ni < 4; ++ni)
            xl[row * 132 + (wn - 2) * 64 + ni * 16 + l15] = acc[mi][ni][jj];
        }
    }
    __syncthreads();
    if (wn < 2) {
#pragma unroll
      for (int mi = 0; mi < 8; ++mi)
#pragma unroll
        for (int jj = 0; jj < 4; ++jj) {
          int row = wm * 128 + mi * 16 + l4 * 4 + jj;
          int r = mt * 256 + row;
          if (r >= cnt) continue;
          size_t hrow = (size_t)(off_e + r);
#pragma unroll
          for (int ni = 0; ni < 4; ++ni) {
            int col = wn * 64 + ni * 16 + l15;
            float x1 = acc[mi][ni][jj];
            float x2 = xl[row * 132 + col];
            float h = (x1 / (1.f + expf(-x1))) * x2;
            H[hrow * NF + nt * 128 + col] = f2bf(h);
          }
        }
    }
  } else {
    unsigned short* Yp = Y + (size_t)kh * NROWS * ND;
#pragma unroll
    for (int mi = 0; mi < 8; ++mi)
#pragma unroll
      for (int jj = 0; jj < 4; ++jj) {
        int r = mt * 256 + wm * 128 + mi * 16 + l4 * 4 + jj;
        if (r >= cnt) continue;
        size_t row = (size_t)(off_e + r);
#pragma unroll
        for (int ni = 0; ni < 4; ++ni) {
          int d = nt * 256 + wn * 64 + ni * 16 + l15;
          Yp[row * ND + d] = f2bf(acc[mi][ni][jj]);
        }
      }
  }
}

// -------- combine: out[t] = tw0*(y[r0,kh0]+y[r0,kh1]) + tw1*(...) -----------
__global__ void combine_kernel(const unsigned short* __restrict__ yc,
                               const float* __restrict__ tw,
                               const int* __restrict__ choice,
                               const int* __restrict__ posn,
                               const int* __restrict__ off,
                               float* __restrict__ out) {
  int t = blockIdx.x;
  int tid = threadIdx.x;   // 256: one float4 (4 elems) each
  int ch = choice[t];
  int pp = posn[t];
  int e0 = ch & 15, e1 = (ch >> 4) & 15;
  size_t r0 = (size_t)(off[e0] + (pp & 0xffff));
  size_t r1 = (size_t)(off[e1] + (pp >> 16));
  float w0 = tw[t * 2], w1 = tw[t * 2 + 1];
  const size_t P = (size_t)NROWS * ND;
  ushort4 a0 = ((const ushort4*)(yc + r0 * ND))[tid];
  ushort4 b0 = ((const ushort4*)(yc + P + r0 * ND))[tid];
  ushort4 a1 = ((const ushort4*)(yc + r1 * ND))[tid];
  ushort4 b1 = ((const ushort4*)(yc + P + r1 * ND))[tid];
  float4 o;
  o.x = w0 * (bf2f(a0.x) + bf2f(b0.x)) + w1 * (bf2f(a1.x) + bf2f(b1.x));
  o.y = w0 * (bf2f(a0.y) + bf2f(b0.y)) + w1 * (bf2f(a1.y) + bf2f(b1.y));
  o.z = w0 * (bf2f(a0.z) + bf2f(b0.z)) + w1 * (bf2f(a1.z) + bf2f(b1.z));
  o.w = w0 * (bf2f(a0.w) + bf2f(b0.w)) + w1 * (bf2f(a1.w) + bf2f(b1.w));
  ((float4*)(out + (size_t)t * ND))[tid] = o;
}

// ---------------- workspace layout (bytes) ----------------
// counts:  0          (64)
// off:     64         (64)
// choice:  128        (16384)     end 16512
// posn:    16512      (16384)     end 32896
// tw:      32896      (32768)     end 65664
// list:    65664      (131072)    end 196736
// hsb:     196736     (8388608)   end 8585344
// w1b:     8585344    (33554432)  end 42139776
// v1b:     42139776   (33554432)  end 75694208
// w2t:     75694208   (33554432)  end 109248640
// hcomp:   109248640  (33554432)  end 142803072   [NROWS][NF] bf16
// ycomp:   142803072  (33554432)  end 176357504   [2][NROWS][ND] bf16

extern "C" void kernel_launch(void* const* d_in, const int* in_sizes, int n_in,
                              void* d_out, int out_size, void* d_ws, size_t ws_size,
                              hipStream_t stream) {
  const float* hs = (const float*)d_in[0];
  const float* rk = (const float*)d_in[1];
  const float* w1 = (const float*)d_in[2];
  const float* v1 = (const float*)d_in[3];
  const float* w2 = (const float*)d_in[4];
  float* out = (float*)d_out;
  float* wout = out + (size_t)NTOK * ND;

  char* ws = (char*)d_ws;
  int* counts = (int*)(ws + 0);
  int* off = (int*)(ws + 64);
  int* choice = (int*)(ws + 128);
  int* posn = (int*)(ws + 16512);
  float* tw = (float*)(ws + 32896);
  int* list = (int*)(ws + 65664);
  unsigned short* hsb = (unsigned short*)(ws + 196736);
  unsigned short* w1b = (unsigned short*)(ws + 8585344);
  unsigned short* v1b = (unsigned short*)(ws + 42139776);
  unsigned short* w2t = (unsigned short*)(ws + 75694208);
  unsigned short* hcomp = (unsigned short*)(ws + 109248640);
  unsigned short* ycomp = (unsigned short*)(ws + 142803072);

  // router (also converts hs -> bf16), then list/offset construction
  router_kernel<<<256, 64, 0, stream>>>(hs, rk, wout, tw, choice, hsb);
  build_lists<<<1, 1024, 0, stream>>>(choice, counts, off, list, posn);

  // weight conversions
  cvt_bf16<<<4096, 256, 0, stream>>>(w1, w1b, (int)(EFD / 4));
  cvt_bf16<<<4096, 256, 0, stream>>>(v1, v1b, (int)(EFD / 4));
  transpose_w2<<<dim3(ND / 32, NF / 32, NE), dim3(32, 8), 0, stream>>>(w2, w2t);

  // fused pass1+2 (8-phase 256x256): h = silu(X@w1^T)*(X@v1^T) -> hcomp
  // grid = 8e x 8mt x 16nt = 1024 (~512 active)
  gemm8<1><<<1024, 512, 0, stream>>>(counts, off, list, hsb, w1b, v1b,
                                     hcomp, nullptr);

  // pass3 (8-phase 256x256): y = h @ w2t^T, split-K=2 -> ycomp bf16
  // grid = 8e x 8mt x 4nt x 2kh = 512 (~256 active)
  gemm8<0><<<512, 512, 0, stream>>>(counts, off, nullptr, hcomp, w2t, nullptr,
                                    nullptr, ycomp);

  // combine: one token per block, gathers compacted bf16 partial rows
  combine_kernel<<<NTOK, 256, 0, stream>>>(ycomp, tw, choice, posn, off, out);
}

// Round 16
// 295.287 us; speedup vs baseline: 1.0380x; 1.0380x over previous
//
#include <hip/hip_runtime.h>
#include <stdint.h>
#include <math.h>

// Problem constants (DBRX FFN): B=2 S=2048 D=1024 E=8 F=2048 K=2
#define NB 2
#define NS 2048
#define ND 1024
#define NE 8
#define NF 2048
#define NTOK (NB*NS)          // 4096 tokens
#define EFD ((size_t)NE*NF*ND)
#define NROWS (2*NTOK)        // 8192 compacted (token,slot) rows

typedef short bf16x8 __attribute__((ext_vector_type(8)));
typedef float f32x4 __attribute__((ext_vector_type(4)));

__device__ __forceinline__ unsigned short f2bf(float f) {
  unsigned u = __float_as_uint(f);
  unsigned r = (u + 0x7FFFu + ((u >> 16) & 1u)) >> 16;
  return (unsigned short)r;
}
__device__ __forceinline__ float bf2f(unsigned short s) {
  return __uint_as_float(((unsigned)s) << 16);
}

__device__ __forceinline__ void async16(unsigned short* lds, const unsigned short* g) {
  __builtin_amdgcn_global_load_lds(
      (const __attribute__((address_space(1))) unsigned int*)g,
      (__attribute__((address_space(3))) unsigned int*)lds, 16, 0, 0);
}

#define VMCNT(n) asm volatile("s_waitcnt vmcnt(" #n ")" ::: "memory")
#define LGKM0    asm volatile("s_waitcnt lgkmcnt(0)" ::: "memory")
#define SBAR     __builtin_amdgcn_s_barrier()
#define SCHED0   __builtin_amdgcn_sched_barrier(0)

// ---------------- convert fp32 -> bf16 (vectorized) ----------------
__global__ void cvt_bf16(const float* __restrict__ src,
                         unsigned short* __restrict__ dst, int n4) {
  int i = blockIdx.x * blockDim.x + threadIdx.x;
  int stride = gridDim.x * blockDim.x;
  for (; i < n4; i += stride) {
    float4 v = ((const float4*)src)[i];
    ushort4 o;
    o.x = f2bf(v.x); o.y = f2bf(v.y); o.z = f2bf(v.z); o.w = f2bf(v.w);
    ((ushort4*)dst)[i] = o;
  }
}

// ---------------- transpose w2 (E,F,D) fp32 -> w2t (E,D,F) bf16 ----------------
__global__ void transpose_w2(const float* __restrict__ w2,
                             unsigned short* __restrict__ w2t) {
  __shared__ float tile[32][33];
  int e = blockIdx.z;
  int d0 = blockIdx.x * 32, f0 = blockIdx.y * 32;
  int tx = threadIdx.x, ty = threadIdx.y;
  const float* src = w2 + (size_t)e * NF * ND;
  unsigned short* dst = w2t + (size_t)e * ND * NF;
#pragma unroll
  for (int i = ty; i < 32; i += 8)
    tile[i][tx] = src[(size_t)(f0 + i) * ND + d0 + tx];
  __syncthreads();
#pragma unroll
  for (int i = ty; i < 32; i += 8)
    dst[(size_t)(d0 + i) * NF + f0 + tx] = f2bf(tile[tx][i]);
}

// ---------------- router: wave per 16 tokens, 4 lanes per token ----------------
__global__ void router_kernel(const float* __restrict__ hs,
                              const float* __restrict__ rk,
                              float* __restrict__ wout,   // [NTOK][NE]
                              float* __restrict__ tw,     // [NTOK][2]
                              int* __restrict__ choice,   // [NTOK] e0 | e1<<4
                              unsigned short* __restrict__ hsb) {
  int lane = threadIdx.x;            // 64
  int tt = lane & 15, part = lane >> 4;
  int t = blockIdx.x * 16 + tt;      // 256 blocks
  const float4* hrow = (const float4*)(hs + (size_t)t * ND) + part * 64;
  ushort4* hb4 = (ushort4*)(hsb + (size_t)t * ND) + part * 64;
  const float4* rk4 = (const float4*)rk + part * 512;
  float acc[NE];
#pragma unroll
  for (int e = 0; e < NE; ++e) acc[e] = 0.f;
#pragma unroll 4
  for (int i = 0; i < 64; ++i) {
    float4 x = hrow[i];
    ushort4 o;
    o.x = f2bf(x.x); o.y = f2bf(x.y); o.z = f2bf(x.z); o.w = f2bf(x.w);
    hb4[i] = o;
    float xs[4] = {x.x, x.y, x.z, x.w};
#pragma unroll
    for (int j = 0; j < 4; ++j) {
      float4 r0 = rk4[i * 8 + j * 2];
      float4 r1 = rk4[i * 8 + j * 2 + 1];
      acc[0] += xs[j] * r0.x; acc[1] += xs[j] * r0.y;
      acc[2] += xs[j] * r0.z; acc[3] += xs[j] * r0.w;
      acc[4] += xs[j] * r1.x; acc[5] += xs[j] * r1.y;
      acc[6] += xs[j] * r1.z; acc[7] += xs[j] * r1.w;
    }
  }
#pragma unroll
  for (int e = 0; e < NE; ++e) {
    acc[e] += __shfl_xor(acc[e], 16, 64);
    acc[e] += __shfl_xor(acc[e], 32, 64);
  }
  if (part == 0) {
    float mx = acc[0]; int i0 = 0;
#pragma unroll
    for (int e = 1; e < NE; ++e) if (acc[e] > mx) { mx = acc[e]; i0 = e; }
    float m2 = -3.4e38f; int i1 = 0;
#pragma unroll
    for (int e = 0; e < NE; ++e) if (e != i0 && acc[e] > m2) { m2 = acc[e]; i1 = e; }
    float p[NE]; float den = 0.f;
#pragma unroll
    for (int e = 0; e < NE; ++e) { p[e] = expf(acc[e] - mx); den += p[e]; }
    float inv = 1.f / den;
#pragma unroll
    for (int e = 0; e < NE; ++e) { p[e] *= inv; wout[t * NE + e] = p[e]; }
    float w0 = p[i0], w1 = p[i1];
    float s = 1.f / (w0 + w1);
    tw[t * 2 + 0] = w0 * s;
    tw[t * 2 + 1] = w1 * s;
    choice[t] = i0 | (i1 << 4);
  }
}

// ------- build lists + per-token positions + expert prefix offsets ----------
__global__ void build_lists(const int* __restrict__ choice,
                            int* __restrict__ counts,
                            int* __restrict__ off,      // [NE+1] prefix
                            int* __restrict__ list,     // [NE][NTOK] token<<1|slot
                            int* __restrict__ posn) {   // [NTOK] p0 | p1<<16
  __shared__ int lcnt[NE];
  int tid = threadIdx.x;  // 1024
  if (tid < NE) lcnt[tid] = 0;
  __syncthreads();
  int4 c4 = ((const int4*)choice)[tid];
  int cs[4] = {c4.x, c4.y, c4.z, c4.w};
#pragma unroll
  for (int j = 0; j < 4; ++j) {
    int t = tid * 4 + j;
    int e0 = cs[j] & 15, e1 = (cs[j] >> 4) & 15;
    int p0 = atomicAdd(&lcnt[e0], 1);
    list[e0 * NTOK + p0] = t << 1;
    int p1 = atomicAdd(&lcnt[e1], 1);
    list[e1 * NTOK + p1] = (t << 1) | 1;
    posn[t] = p0 | (p1 << 16);
  }
  __syncthreads();
  if (tid == 0) {
    int s = 0;
#pragma unroll
    for (int e = 0; e < NE; ++e) { counts[e] = lcnt[e]; off[e] = s; s += lcnt[e]; }
    off[NE] = s;
  }
}

// ============ 8-phase 256x256 GEMM (m201-style), FUSED / P3 ==================
// Identical to R15 EXCEPT the swizzle is reverted to the R5-proven variant
// slot ^ ((row>>1)&3) (R15 used row&3 -> 4-way bank conflict, 6.88M measured).
// 512 thr = 8 waves (2M x 4N). Wave tile 128x64, acc[8][4]. BK=64, kT=16.
// LDS: 2 bufs x 64KB [A.ks0|A.ks1|B.ks0|B.ks1] (16KB regions); epilogue
// overlay xl[256][132] fp32. Per phase: {4 ds_read_b128 (+4 B at even);
// 1 half-tile stage (2 gload_lds); SBAR; lgkm0; setprio(1); 16 MFMA;
// setprio(0); [odd: counted VMCNT(8), tail 4/0]; SBAR}.
template <int FUSED>
__global__ __launch_bounds__(512, 2) void gemm8(
    const int* __restrict__ counts, const int* __restrict__ off,
    const int* __restrict__ list,
    const unsigned short* __restrict__ A,
    const unsigned short* __restrict__ B1,
    const unsigned short* __restrict__ B2,
    unsigned short* __restrict__ H,
    unsigned short* __restrict__ Y) {
  int bid = blockIdx.x;
  int e, mt, nt, kh = 0;
  if (FUSED) { e = bid >> 7; int r = bid & 127; mt = r >> 4; nt = r & 15; }
  else       { e = bid >> 6; int r = bid & 63;  mt = r >> 3; int c = r & 7; nt = c >> 1; kh = c & 1; }
  int cnt = counts[e];
  if (mt * 256 >= cnt) return;
  int off_e = off[e];

  __shared__ char smem[135168];   // 2 x 64KB ring + epilogue overlay

  int tid = threadIdx.x;
  int wid = tid >> 6, lane = tid & 63;
  int wm = wid >> 2, wn = wid & 3;
  int l15 = lane & 15, l4 = lane >> 4;
  const int* mylist = list + e * NTOK;

  // ---- staging sources: thread covers slots tid (row tid>>2) and tid+512 ----
  const unsigned short* aS0; const unsigned short* aS1;
  const unsigned short* bS0; const unsigned short* bS1;
  {
#pragma unroll
    for (int i = 0; i < 2; ++i) {
      int slot = tid + i * 512;
      int row = slot >> 2;                            // 0..255
      int co = ((slot & 3) ^ ((row >> 1) & 3)) * 8;   // inverse swizzle (R5)
      const unsigned short* ap;
      const unsigned short* bp;
      int r = mt * 256 + row;
      if (r >= cnt) r = cnt - 1;
      if (FUSED) {
        int entry = mylist[r];
        ap = A + (size_t)(entry >> 1) * ND + co;
        bp = (row < 128)
           ? B1 + (size_t)e * NF * ND + (size_t)(nt * 128 + row) * ND + co
           : B2 + (size_t)e * NF * ND + (size_t)(nt * 128 + row - 128) * ND + co;
      } else {
        ap = A + (size_t)(off_e + r) * NF + kh * 1024 + co;
        bp = B1 + (size_t)e * ND * NF + (size_t)(nt * 256 + row) * NF + kh * 1024 + co;
      }
      if (i == 0) { aS0 = ap; bS0 = bp; } else { aS1 = ap; bS1 = bp; }
    }
  }

  // ---- swizzled fragment read byte offsets (relative to region base) ----
  int offA[8], offB[4];
#pragma unroll
  for (int mi = 0; mi < 8; ++mi) {
    int row = wm * 128 + mi * 16 + l15;
    offA[mi] = row * 64 + ((l4 ^ ((row >> 1) & 3)) << 4);
  }
#pragma unroll
  for (int ni = 0; ni < 4; ++ni) {
    int row = wn * 64 + ni * 16 + l15;
    offB[ni] = row * 64 + ((l4 ^ ((row >> 1) & 3)) << 4);
  }

  f32x4 acc[8][4];
#pragma unroll
  for (int mi = 0; mi < 8; ++mi)
#pragma unroll
    for (int ni = 0; ni < 4; ++ni) {
      f32x4 z = {0.f, 0.f, 0.f, 0.f};
      acc[mi][ni] = z;
    }

  // stage one half-tile (2 loads/thread). Regions: buf*65536 + isB*32768 + ks*16384
  auto STAGE_A = [&](int buf, int ks, int tile) {
    if (tile < 16) {
      int ko = tile * 64 + ks * 32;
      unsigned short* base = (unsigned short*)(smem + buf * 65536 + ks * 16384) + tid * 8;
      async16(base, aS0 + ko);
      async16(base + 4096, aS1 + ko);
    }
  };
  auto STAGE_B = [&](int buf, int ks, int tile) {
    if (tile < 16) {
      int ko = tile * 64 + ks * 32;
      unsigned short* base = (unsigned short*)(smem + buf * 65536 + 32768 + ks * 16384) + tid * 8;
      async16(base, bS0 + ko);
      async16(base + 4096, bS1 + ko);
    }
  };

  // ---- prologue: t0 all 4 halves -> buf0; t1 ks0 halves -> buf1 ----
  STAGE_A(0, 0, 0); STAGE_B(0, 0, 0);
  STAGE_A(0, 1, 0); STAGE_B(0, 1, 0);
  STAGE_A(1, 0, 1); STAGE_B(1, 0, 1);
  VMCNT(8);     // t0.ks0 (first 4 loads) landed
  SCHED0;
  SBAR;

  bf16x8 bq0, bq1, bq2, bq3;

#define PH(Q, BUF, MIB, KS, STG, VMT) \
  { \
    const char* ab = smem + (BUF) * 65536 + (KS) * 16384; \
    const char* bb = ab + 32768; \
    bf16x8 a0 = *(const bf16x8*)(ab + offA[(MIB) + 0]); \
    bf16x8 a1 = *(const bf16x8*)(ab + offA[(MIB) + 1]); \
    bf16x8 a2 = *(const bf16x8*)(ab + offA[(MIB) + 2]); \
    bf16x8 a3 = *(const bf16x8*)(ab + offA[(MIB) + 3]); \
    if ((Q) % 2 == 0) { \
      bq0 = *(const bf16x8*)(bb + offB[0]); \
      bq1 = *(const bf16x8*)(bb + offB[1]); \
      bq2 = *(const bf16x8*)(bb + offB[2]); \
      bq3 = *(const bf16x8*)(bb + offB[3]); \
    } \
    STG; \
    SBAR; \
    LGKM0; SCHED0; \
    __builtin_amdgcn_s_setprio(1); \
    acc[(MIB)+0][0] = __builtin_amdgcn_mfma_f32_16x16x32_bf16(a0, bq0, acc[(MIB)+0][0], 0, 0, 0); \
    acc[(MIB)+0][1] = __builtin_amdgcn_mfma_f32_16x16x32_bf16(a0, bq1, acc[(MIB)+0][1], 0, 0, 0); \
    acc[(MIB)+0][2] = __builtin_amdgcn_mfma_f32_16x16x32_bf16(a0, bq2, acc[(MIB)+0][2], 0, 0, 0); \
    acc[(MIB)+0][3] = __builtin_amdgcn_mfma_f32_16x16x32_bf16(a0, bq3, acc[(MIB)+0][3], 0, 0, 0); \
    acc[(MIB)+1][0] = __builtin_amdgcn_mfma_f32_16x16x32_bf16(a1, bq0, acc[(MIB)+1][0], 0, 0, 0); \
    acc[(MIB)+1][1] = __builtin_amdgcn_mfma_f32_16x16x32_bf16(a1, bq1, acc[(MIB)+1][1], 0, 0, 0); \
    acc[(MIB)+1][2] = __builtin_amdgcn_mfma_f32_16x16x32_bf16(a1, bq2, acc[(MIB)+1][2], 0, 0, 0); \
    acc[(MIB)+1][3] = __builtin_amdgcn_mfma_f32_16x16x32_bf16(a1, bq3, acc[(MIB)+1][3], 0, 0, 0); \
    acc[(MIB)+2][0] = __builtin_amdgcn_mfma_f32_16x16x32_bf16(a2, bq0, acc[(MIB)+2][0], 0, 0, 0); \
    acc[(MIB)+2][1] = __builtin_amdgcn_mfma_f32_16x16x32_bf16(a2, bq1, acc[(MIB)+2][1], 0, 0, 0); \
    acc[(MIB)+2][2] = __builtin_amdgcn_mfma_f32_16x16x32_bf16(a2, bq2, acc[(MIB)+2][2], 0, 0, 0); \
    acc[(MIB)+2][3] = __builtin_amdgcn_mfma_f32_16x16x32_bf16(a2, bq3, acc[(MIB)+2][3], 0, 0, 0); \
    acc[(MIB)+3][0] = __builtin_amdgcn_mfma_f32_16x16x32_bf16(a3, bq0, acc[(MIB)+3][0], 0, 0, 0); \
    acc[(MIB)+3][1] = __builtin_amdgcn_mfma_f32_16x16x32_bf16(a3, bq1, acc[(MIB)+3][1], 0, 0, 0); \
    acc[(MIB)+3][2] = __builtin_amdgcn_mfma_f32_16x16x32_bf16(a3, bq2, acc[(MIB)+3][2], 0, 0, 0); \
    acc[(MIB)+3][3] = __builtin_amdgcn_mfma_f32_16x16x32_bf16(a3, bq3, acc[(MIB)+3][3], 0, 0, 0); \
    __builtin_amdgcn_s_setprio(0); \
    VMT; \
    SBAR; \
  }

  for (int j = 0; j < 8; ++j) {
    int t1 = 2 * j + 1, t2 = 2 * j + 2, t3 = 2 * j + 3;
    bool last = (j == 7);
    PH(0, 0, 0, 0, STAGE_A(1, 1, t1), {});
    PH(1, 0, 4, 0, STAGE_B(1, 1, t1), { VMCNT(8); SCHED0; });
    PH(2, 0, 0, 1, STAGE_A(0, 0, t2), {});
    PH(3, 0, 4, 1, STAGE_B(0, 0, t2), { if (last) { VMCNT(4); } else { VMCNT(8); } SCHED0; });
    PH(4, 1, 0, 0, STAGE_A(0, 1, t2), {});
    PH(5, 1, 4, 0, STAGE_B(0, 1, t2), { if (last) { VMCNT(0); } else { VMCNT(8); } SCHED0; });
    PH(6, 1, 0, 1, STAGE_A(1, 0, t3), {});
    PH(7, 1, 4, 1, STAGE_B(1, 0, t3), { if (!last) { VMCNT(8); SCHED0; } });
  }
#undef PH

  // ---- epilogue ----
  if (FUSED) {
    float* xl = (float*)smem;         // [256][132] fp32 overlay
    if (wn >= 2) {
#pragma unroll
      for (int mi = 0; mi < 8; ++mi)
#pragma unroll
        for (int jj = 0; jj < 4; ++jj) {
          int row = wm * 128 + mi * 16 + l4 * 4 + jj;
#pragma unroll
          for (int ni = 0; ni < 4; ++ni)
            xl[row * 132 + (wn - 2) * 64 + ni * 16 + l15] = acc[mi][ni][jj];
        }
    }
    __syncthreads();
    if (wn < 2) {
#pragma unroll
      for (int mi = 0; mi < 8; ++mi)
#pragma unroll
        for (int jj = 0; jj < 4; ++jj) {
          int row = wm * 128 + mi * 16 + l4 * 4 + jj;
          int r = mt * 256 + row;
          if (r >= cnt) continue;
          size_t hrow = (size_t)(off_e + r);
#pragma unroll
          for (int ni = 0; ni < 4; ++ni) {
            int col = wn * 64 + ni * 16 + l15;
            float x1 = acc[mi][ni][jj];
            float x2 = xl[row * 132 + col];
            float h = (x1 / (1.f + expf(-x1))) * x2;
            H[hrow * NF + nt * 128 + col] = f2bf(h);
          }
        }
    }
  } else {
    unsigned short* Yp = Y + (size_t)kh * NROWS * ND;
#pragma unroll
    for (int mi = 0; mi < 8; ++mi)
#pragma unroll
      for (int jj = 0; jj < 4; ++jj) {
        int r = mt * 256 + wm * 128 + mi * 16 + l4 * 4 + jj;
        if (r >= cnt) continue;
        size_t row = (size_t)(off_e + r);
#pragma unroll
        for (int ni = 0; ni < 4; ++ni) {
          int d = nt * 256 + wn * 64 + ni * 16 + l15;
          Yp[row * ND + d] = f2bf(acc[mi][ni][jj]);
        }
      }
  }
}

// -------- combine: out[t] = tw0*(y[r0,kh0]+y[r0,kh1]) + tw1*(...) -----------
__global__ void combine_kernel(const unsigned short* __restrict__ yc,
                               const float* __restrict__ tw,
                               const int* __restrict__ choice,
                               const int* __restrict__ posn,
                               const int* __restrict__ off,
                               float* __restrict__ out) {
  int t = blockIdx.x;
  int tid = threadIdx.x;   // 256: one float4 (4 elems) each
  int ch = choice[t];
  int pp = posn[t];
  int e0 = ch & 15, e1 = (ch >> 4) & 15;
  size_t r0 = (size_t)(off[e0] + (pp & 0xffff));
  size_t r1 = (size_t)(off[e1] + (pp >> 16));
  float w0 = tw[t * 2], w1 = tw[t * 2 + 1];
  const size_t P = (size_t)NROWS * ND;
  ushort4 a0 = ((const ushort4*)(yc + r0 * ND))[tid];
  ushort4 b0 = ((const ushort4*)(yc + P + r0 * ND))[tid];
  ushort4 a1 = ((const ushort4*)(yc + r1 * ND))[tid];
  ushort4 b1 = ((const ushort4*)(yc + P + r1 * ND))[tid];
  float4 o;
  o.x = w0 * (bf2f(a0.x) + bf2f(b0.x)) + w1 * (bf2f(a1.x) + bf2f(b1.x));
  o.y = w0 * (bf2f(a0.y) + bf2f(b0.y)) + w1 * (bf2f(a1.y) + bf2f(b1.y));
  o.z = w0 * (bf2f(a0.z) + bf2f(b0.z)) + w1 * (bf2f(a1.z) + bf2f(b1.z));
  o.w = w0 * (bf2f(a0.w) + bf2f(b0.w)) + w1 * (bf2f(a1.w) + bf2f(b1.w));
  ((float4*)(out + (size_t)t * ND))[tid] = o;
}

// ---------------- workspace layout (bytes) ----------------
// counts:  0          (64)
// off:     64         (64)
// choice:  128        (16384)     end 16512
// posn:    16512      (16384)     end 32896
// tw:      32896      (32768)     end 65664
// list:    65664      (131072)    end 196736
// hsb:     196736     (8388608)   end 8585344
// w1b:     8585344    (33554432)  end 42139776
// v1b:     42139776   (33554432)  end 75694208
// w2t:     75694208   (33554432)  end 109248640
// hcomp:   109248640  (33554432)  end 142803072   [NROWS][NF] bf16
// ycomp:   142803072  (33554432)  end 176357504   [2][NROWS][ND] bf16

extern "C" void kernel_launch(void* const* d_in, const int* in_sizes, int n_in,
                              void* d_out, int out_size, void* d_ws, size_t ws_size,
                              hipStream_t stream) {
  const float* hs = (const float*)d_in[0];
  const float* rk = (const float*)d_in[1];
  const float* w1 = (const float*)d_in[2];
  const float* v1 = (const float*)d_in[3];
  const float* w2 = (const float*)d_in[4];
  float* out = (float*)d_out;
  float* wout = out + (size_t)NTOK * ND;

  char* ws = (char*)d_ws;
  int* counts = (int*)(ws + 0);
  int* off = (int*)(ws + 64);
  int* choice = (int*)(ws + 128);
  int* posn = (int*)(ws + 16512);
  float* tw = (float*)(ws + 32896);
  int* list = (int*)(ws + 65664);
  unsigned short* hsb = (unsigned short*)(ws + 196736);
  unsigned short* w1b = (unsigned short*)(ws + 8585344);
  unsigned short* v1b = (unsigned short*)(ws + 42139776);
  unsigned short* w2t = (unsigned short*)(ws + 75694208);
  unsigned short* hcomp = (unsigned short*)(ws + 109248640);
  unsigned short* ycomp = (unsigned short*)(ws + 142803072);

  // router (also converts hs -> bf16), then list/offset construction
  router_kernel<<<256, 64, 0, stream>>>(hs, rk, wout, tw, choice, hsb);
  build_lists<<<1, 1024, 0, stream>>>(choice, counts, off, list, posn);

  // weight conversions
  cvt_bf16<<<4096, 256, 0, stream>>>(w1, w1b, (int)(EFD / 4));
  cvt_bf16<<<4096, 256, 0, stream>>>(v1, v1b, (int)(EFD / 4));
  transpose_w2<<<dim3(ND / 32, NF / 32, NE), dim3(32, 8), 0, stream>>>(w2, w2t);

  // fused pass1+2 (8-phase 256x256): h = silu(X@w1^T)*(X@v1^T) -> hcomp
  // grid = 8e x 8mt x 16nt = 1024 (~512 active)
  gemm8<1><<<1024, 512, 0, stream>>>(counts, off, list, hsb, w1b, v1b,
                                     hcomp, nullptr);

  // pass3 (8-phase 256x256): y = h @ w2t^T, split-K=2 -> ycomp bf16
  // grid = 8e x 8mt x 4nt x 2kh = 512 (~256 active)
  gemm8<0><<<512, 512, 0, stream>>>(counts, off, nullptr, hcomp, w2t, nullptr,
                                    nullptr, ycomp);

  // combine: one token per block, gathers compacted bf16 partial rows
  combine_kernel<<<NTOK, 256, 0, stream>>>(ycomp, tw, choice, posn, off, out);
}

// Round 17
// 239.114 us; speedup vs baseline: 1.2819x; 1.2349x over previous
//
#include <hip/hip_runtime.h>
#include <stdint.h>
#include <math.h>

// Problem constants (DBRX FFN): B=2 S=2048 D=1024 E=8 F=2048 K=2
#define NB 2
#define NS 2048
#define ND 1024
#define NE 8
#define NF 2048
#define NTOK (NB*NS)          // 4096 tokens
#define EFD ((size_t)NE*NF*ND)
#define NROWS (2*NTOK)        // 8192 compacted (token,slot) rows

typedef short bf16x8 __attribute__((ext_vector_type(8)));
typedef unsigned short u16x8 __attribute__((ext_vector_type(8)));
typedef float f32x4 __attribute__((ext_vector_type(4)));

__device__ __forceinline__ unsigned short f2bf(float f) {
  unsigned u = __float_as_uint(f);
  unsigned r = (u + 0x7FFFu + ((u >> 16) & 1u)) >> 16;
  return (unsigned short)r;
}
__device__ __forceinline__ float bf2f(unsigned short s) {
  return __uint_as_float(((unsigned)s) << 16);
}

__device__ __forceinline__ void async16(unsigned short* lds, const unsigned short* g) {
  __builtin_amdgcn_global_load_lds(
      (const __attribute__((address_space(1))) unsigned int*)g,
      (__attribute__((address_space(3))) unsigned int*)lds, 16, 0, 0);
}

#define VMCNT(n) asm volatile("s_waitcnt vmcnt(" #n ")" ::: "memory")
#define LGKM0    asm volatile("s_waitcnt lgkmcnt(0)" ::: "memory")
#define SBAR     __builtin_amdgcn_s_barrier()
#define SCHED0   __builtin_amdgcn_sched_barrier(0)

// ------- convert fp32 -> bf16, two sources in one launch (w1b|v1b contig) ----
__global__ void cvt_bf16_2(const float* __restrict__ s1,
                           const float* __restrict__ s2,
                           unsigned short* __restrict__ dst, int n4each) {
  int i = blockIdx.x * blockDim.x + threadIdx.x;
  int stride = gridDim.x * blockDim.x;
  int total = 2 * n4each;
  for (; i < total; i += stride) {
    const float4* src = (i < n4each) ? (const float4*)s1 : (const float4*)s2;
    int k = (i < n4each) ? i : i - n4each;
    float4 v = src[k];
    ushort4 o;
    o.x = f2bf(v.x); o.y = f2bf(v.y); o.z = f2bf(v.z); o.w = f2bf(v.w);
    ((ushort4*)dst)[i] = o;
  }
}

// ------- transpose w2 (E,F,D) fp32 -> w2t (E,D,F) bf16, vectorized IO --------
// 64x64 tile per 256-thr block. float4 global reads, ushort8 (16B) writes.
__global__ void transpose_w2(const float* __restrict__ w2,
                             unsigned short* __restrict__ w2t) {
  __shared__ float tile[64][65];
  int e = blockIdx.z;
  int d0 = blockIdx.x * 64, f0 = blockIdx.y * 64;
  int tid = threadIdx.x;   // 256
  const float* src = w2 + (size_t)e * NF * ND;
  unsigned short* dst = w2t + (size_t)e * ND * NF;
  int c4 = tid & 15;                 // float4 col within tile
#pragma unroll
  for (int i = 0; i < 4; ++i) {
    int fr = (tid >> 4) + i * 16;    // 0..63
    float4 v = *(const float4*)(src + (size_t)(f0 + fr) * ND + d0 + c4 * 4);
    tile[fr][c4 * 4 + 0] = v.x;
    tile[fr][c4 * 4 + 1] = v.y;
    tile[fr][c4 * 4 + 2] = v.z;
    tile[fr][c4 * 4 + 3] = v.w;
  }
  __syncthreads();
  int f8 = tid & 7;                  // 8-col group within tile
#pragma unroll
  for (int i = 0; i < 2; ++i) {
    int dr = (tid >> 3) + i * 32;    // 0..63
    u16x8 o;
#pragma unroll
    for (int k = 0; k < 8; ++k)
      o[k] = f2bf(tile[f8 * 8 + k][dr]);
    *(u16x8*)(dst + (size_t)(d0 + dr) * NF + f0 + f8 * 8) = o;
  }
}

// ------- router: 4 tokens per wave (16 lanes/token), 1024 blocks ------------
// Fuses hs fp32->bf16. 4 waves/CU (vs 1 before).
__global__ void router_kernel(const float* __restrict__ hs,
                              const float* __restrict__ rk,
                              float* __restrict__ wout,   // [NTOK][NE]
                              float* __restrict__ tw,     // [NTOK][2]
                              int* __restrict__ choice,   // [NTOK] e0 | e1<<4
                              unsigned short* __restrict__ hsb) {
  int lane = threadIdx.x;            // 64
  int tt = lane >> 4, part = lane & 15;
  int t = blockIdx.x * 4 + tt;       // 1024 blocks
  const float4* hrow = (const float4*)(hs + (size_t)t * ND);
  ushort4* hb4 = (ushort4*)(hsb + (size_t)t * ND);
  const float4* rk4 = (const float4*)rk;   // rk[d][e] -> 2 float4 per d
  float acc[NE];
#pragma unroll
  for (int e = 0; e < NE; ++e) acc[e] = 0.f;
#pragma unroll 4
  for (int i = 0; i < 16; ++i) {
    int fi = part + i * 16;          // float4 index within row (0..255)
    float4 x = hrow[fi];
    ushort4 o;
    o.x = f2bf(x.x); o.y = f2bf(x.y); o.z = f2bf(x.z); o.w = f2bf(x.w);
    hb4[fi] = o;
    float xs[4] = {x.x, x.y, x.z, x.w};
#pragma unroll
    for (int j = 0; j < 4; ++j) {
      int d = fi * 4 + j;
      float4 r0 = rk4[d * 2];
      float4 r1 = rk4[d * 2 + 1];
      acc[0] += xs[j] * r0.x; acc[1] += xs[j] * r0.y;
      acc[2] += xs[j] * r0.z; acc[3] += xs[j] * r0.w;
      acc[4] += xs[j] * r1.x; acc[5] += xs[j] * r1.y;
      acc[6] += xs[j] * r1.z; acc[7] += xs[j] * r1.w;
    }
  }
#pragma unroll
  for (int m = 1; m <= 8; m <<= 1) {
#pragma unroll
    for (int e = 0; e < NE; ++e) acc[e] += __shfl_xor(acc[e], m, 64);
  }
  if (part == 0) {
    float mx = acc[0]; int i0 = 0;
#pragma unroll
    for (int e = 1; e < NE; ++e) if (acc[e] > mx) { mx = acc[e]; i0 = e; }
    float m2 = -3.4e38f; int i1 = 0;
#pragma unroll
    for (int e = 0; e < NE; ++e) if (e != i0 && acc[e] > m2) { m2 = acc[e]; i1 = e; }
    float p[NE]; float den = 0.f;
#pragma unroll
    for (int e = 0; e < NE; ++e) { p[e] = expf(acc[e] - mx); den += p[e]; }
    float inv = 1.f / den;
#pragma unroll
    for (int e = 0; e < NE; ++e) { p[e] *= inv; wout[t * NE + e] = p[e]; }
    float w0 = p[i0], w1 = p[i1];
    float s = 1.f / (w0 + w1);
    tw[t * 2 + 0] = w0 * s;
    tw[t * 2 + 1] = w1 * s;
    choice[t] = i0 | (i1 << 4);
  }
}

// ------- build lists + per-token positions + expert prefix offsets ----------
__global__ void build_lists(const int* __restrict__ choice,
                            int* __restrict__ counts,
                            int* __restrict__ off,      // [NE+1] prefix
                            int* __restrict__ list,     // [NE][NTOK] token<<1|slot
                            int* __restrict__ posn) {   // [NTOK] p0 | p1<<16
  __shared__ int lcnt[NE];
  int tid = threadIdx.x;  // 1024
  if (tid < NE) lcnt[tid] = 0;
  __syncthreads();
  int4 c4 = ((const int4*)choice)[tid];
  int cs[4] = {c4.x, c4.y, c4.z, c4.w};
#pragma unroll
  for (int j = 0; j < 4; ++j) {
    int t = tid * 4 + j;
    int e0 = cs[j] & 15, e1 = (cs[j] >> 4) & 15;
    int p0 = atomicAdd(&lcnt[e0], 1);
    list[e0 * NTOK + p0] = t << 1;
    int p1 = atomicAdd(&lcnt[e1], 1);
    list[e1 * NTOK + p1] = (t << 1) | 1;
    posn[t] = p0 | (p1 << 16);
  }
  __syncthreads();
  if (tid == 0) {
    int s = 0;
#pragma unroll
    for (int e = 0; e < NE; ++e) { counts[e] = lcnt[e]; off[e] = s; s += lcnt[e]; }
    off[NE] = s;
  }
}

// ============ fused pass1+2: R14 structure (best measured) ==================
// 256 thr = 4 waves (2x2). BM=128, BN=128 per matrix (w1,v1), BK=32.
// Ring-2 24KB LDS bufs (48KB -> 3 blocks/CU by LDS), launch_bounds(256,2)
// (R13 lesson: (256,3) squeezes VGPR -> spills). Stage-ahead-1, VMCNT(6/0),
// chunk-XOR swizzle slot^((row>>1)&3), 32 MFMA/kt/wave. Compacted H store.
__global__ __launch_bounds__(256, 2) void gemm_fused(
    const int* __restrict__ counts, const int* __restrict__ off,
    const int* __restrict__ list,
    const unsigned short* __restrict__ A,    // hsb [NTOK][ND]
    const unsigned short* __restrict__ B1,   // w1b [E][F][D]
    const unsigned short* __restrict__ B2,   // v1b
    unsigned short* __restrict__ H) {        // hcomp [NROWS][NF]
  int bid = blockIdx.x;
  int e = bid >> 9;                 // 8e x 32mt x 16nt
  int rem = bid & 511;
  int mt = rem >> 4, nt = rem & 15; // nt fastest
  int cnt = counts[e];
  if (mt * 128 >= cnt) return;
  int off_e = off[e];

  __shared__ unsigned short lds[2][12288];   // 2 x 24KB = 48KB

  int tid = threadIdx.x;
  int wid = tid >> 6, lane = tid & 63;
  int wr = wid >> 1, wc = wid & 1;
  int l15 = lane & 15, l4 = lane >> 4;
  const int* mylist = list + e * NTOK;

  int trow = tid >> 2;
  int co = ((tid & 3) ^ ((tid >> 3) & 3)) * 8;
  const unsigned short* aS0;
  const unsigned short* aS1;
  {
    int r0 = mt * 128 + trow;
    int r1 = r0 + 64;
    if (r0 >= cnt) r0 = cnt - 1;
    if (r1 >= cnt) r1 = cnt - 1;
    int e0 = mylist[r0], e1 = mylist[r1];
    aS0 = A + (size_t)(e0 >> 1) * ND + co;
    aS1 = A + (size_t)(e1 >> 1) * ND + co;
  }
  const unsigned short* b1S0 = B1 + (size_t)e * NF * ND + (size_t)(nt * 128 + trow) * ND + co;
  const unsigned short* b1S1 = b1S0 + (size_t)64 * ND;
  const unsigned short* b2S0 = B2 + (size_t)e * NF * ND + (size_t)(nt * 128 + trow) * ND + co;
  const unsigned short* b2S1 = b2S0 + (size_t)64 * ND;

  int rowA[4], rowB[4];
#pragma unroll
  for (int mi = 0; mi < 4; ++mi) {
    int r = wr * 64 + mi * 16 + l15;
    rowA[mi] = r * 64 + ((l4 ^ ((r >> 1) & 3)) << 4);
  }
#pragma unroll
  for (int ni = 0; ni < 4; ++ni) {
    int r = wc * 64 + ni * 16 + l15;
    rowB[ni] = r * 64 + ((l4 ^ ((r >> 1) & 3)) << 4);
  }

  f32x4 acc1[4][4], acc2[4][4];
#pragma unroll
  for (int mi = 0; mi < 4; ++mi)
#pragma unroll
    for (int ni = 0; ni < 4; ++ni) {
      f32x4 z = {0.f, 0.f, 0.f, 0.f};
      acc1[mi][ni] = z; acc2[mi][ni] = z;
    }

  auto STAGE = [&](int c, int kt) {
    int ko = kt * 32;
    unsigned short* base = &lds[c][0] + tid * 8;
    async16(base,         aS0 + ko);
    async16(base + 2048,  aS1 + ko);
    async16(base + 4096,  b1S0 + ko);
    async16(base + 6144,  b1S1 + ko);
    async16(base + 8192,  b2S0 + ko);
    async16(base + 10240, b2S1 + ko);
  };

  const int kT = ND / 32;  // 32
  STAGE(0, 0); STAGE(1, 1);

  for (int kt = 0; kt < kT; ++kt) {
    int cur = kt & 1;
    if (kt + 1 < kT) { VMCNT(6); }
    else             { VMCNT(0); }
    SCHED0;
    SBAR;

    const char* la = (const char*)&lds[cur][0];
    const char* lb1 = la + 8192;
    const char* lb2 = la + 16384;
    bf16x8 a[4], b1[4], b2[4];
#pragma unroll
    for (int mi = 0; mi < 4; ++mi)
      a[mi] = *(const bf16x8*)(la + rowA[mi]);
#pragma unroll
    for (int ni = 0; ni < 4; ++ni) {
      b1[ni] = *(const bf16x8*)(lb1 + rowB[ni]);
      b2[ni] = *(const bf16x8*)(lb2 + rowB[ni]);
    }
    LGKM0;
    SCHED0;
    SBAR;
    if (kt + 2 < kT) STAGE(cur, kt + 2);

    __builtin_amdgcn_s_setprio(1);
#pragma unroll
    for (int mi = 0; mi < 4; ++mi)
#pragma unroll
      for (int ni = 0; ni < 4; ++ni) {
        acc1[mi][ni] = __builtin_amdgcn_mfma_f32_16x16x32_bf16(
            a[mi], b1[ni], acc1[mi][ni], 0, 0, 0);
        acc2[mi][ni] = __builtin_amdgcn_mfma_f32_16x16x32_bf16(
            a[mi], b2[ni], acc2[mi][ni], 0, 0, 0);
      }
    __builtin_amdgcn_s_setprio(0);
  }

  int rowbase = mt * 128 + wr * 64;
  int colbase = nt * 128 + wc * 64;
#pragma unroll
  for (int mi = 0; mi < 4; ++mi) {
#pragma unroll
    for (int j = 0; j < 4; ++j) {
      int r = rowbase + mi * 16 + l4 * 4 + j;
      if (r >= cnt) continue;
      size_t row = (size_t)(off_e + r);
#pragma unroll
      for (int ni = 0; ni < 4; ++ni) {
        int c = colbase + ni * 16 + l15;
        float x1 = acc1[mi][ni][j];
        float x2 = acc2[mi][ni][j];
        float h = (x1 / (1.f + expf(-x1))) * x2;
        H[row * NF + c] = f2bf(h);
      }
    }
  }
}

// ============ pass3: y = h @ w2t^T, ring-2 (R14 structure) ==================
// 256 thr = 4 waves. A = hcomp rows (sequential), B = w2t rows.
// BM=128, BN=256, split-K=2. acc[4][8], 32 MFMA/kt. launch_bounds(256,2).
__global__ __launch_bounds__(256, 2) void gemm_p3(
    const int* __restrict__ counts, const int* __restrict__ off,
    const unsigned short* __restrict__ Ah,   // hcomp [NROWS][NF]
    const unsigned short* __restrict__ Bw,   // w2t [E][ND][NF]
    unsigned short* __restrict__ Y) {        // ycomp [2 kh][NROWS][ND] bf16
  int bid = blockIdx.x;
  int e = bid >> 8;
  int rem = bid & 255;
  int mt = rem >> 3;
  int code = rem & 7;
  int nt = code >> 1, kh = code & 1;
  int cnt = counts[e];
  if (mt * 128 >= cnt) return;
  int off_e = off[e];

  __shared__ unsigned short lds[2][12288];   // 2 x 24KB (A 8KB + B 16KB)

  int tid = threadIdx.x;
  int wid = tid >> 6, lane = tid & 63;
  int wr = wid >> 1, wc = wid & 1;
  int l15 = lane & 15, l4 = lane >> 4;

  int trow = tid >> 2;
  int co = ((tid & 3) ^ ((tid >> 3) & 3)) * 8;
  const unsigned short* aS[2];
#pragma unroll
  for (int g = 0; g < 2; ++g) {
    int r = mt * 128 + g * 64 + trow;
    if (r >= cnt) r = cnt - 1;
    aS[g] = Ah + (size_t)(off_e + r) * NF + kh * 1024 + co;
  }
  const unsigned short* bS[4];
#pragma unroll
  for (int g = 0; g < 4; ++g) {
    int d = nt * 256 + g * 64 + trow;
    bS[g] = Bw + (size_t)e * ND * NF + (size_t)d * NF + kh * 1024 + co;
  }

  int rowA[4], rowB[8];
#pragma unroll
  for (int mi = 0; mi < 4; ++mi) {
    int r = wr * 64 + mi * 16 + l15;
    rowA[mi] = r * 64 + ((l4 ^ ((r >> 1) & 3)) << 4);
  }
#pragma unroll
  for (int ni = 0; ni < 8; ++ni) {
    int r = wc * 128 + ni * 16 + l15;
    rowB[ni] = 8192 + r * 64 + ((l4 ^ ((r >> 1) & 3)) << 4);
  }

  f32x4 acc[4][8];
#pragma unroll
  for (int mi = 0; mi < 4; ++mi)
#pragma unroll
    for (int ni = 0; ni < 8; ++ni) {
      f32x4 z = {0.f, 0.f, 0.f, 0.f};
      acc[mi][ni] = z;
    }

  auto STAGE = [&](int c, int kt) {
    int ko = kt * 32;
    unsigned short* base = &lds[c][0] + tid * 8;
    async16(base,         aS[0] + ko);
    async16(base + 2048,  aS[1] + ko);
    async16(base + 4096,  bS[0] + ko);
    async16(base + 6144,  bS[1] + ko);
    async16(base + 8192,  bS[2] + ko);
    async16(base + 10240, bS[3] + ko);
  };

  const int kT = 32;   // 1024 (per kh) / 32
  STAGE(0, 0); STAGE(1, 1);

  for (int kt = 0; kt < kT; ++kt) {
    int cur = kt & 1;
    if (kt + 1 < kT) { VMCNT(6); }
    else             { VMCNT(0); }
    SCHED0;
    SBAR;

    const char* buf = (const char*)&lds[cur][0];
    bf16x8 a[4], b[8];
#pragma unroll
    for (int mi = 0; mi < 4; ++mi)
      a[mi] = *(const bf16x8*)(buf + rowA[mi]);
#pragma unroll
    for (int ni = 0; ni < 8; ++ni)
      b[ni] = *(const bf16x8*)(buf + rowB[ni]);
    LGKM0;
    SCHED0;
    SBAR;
    if (kt + 2 < kT) STAGE(cur, kt + 2);

    __builtin_amdgcn_s_setprio(1);
#pragma unroll
    for (int mi = 0; mi < 4; ++mi)
#pragma unroll
      for (int ni = 0; ni < 8; ++ni)
        acc[mi][ni] = __builtin_amdgcn_mfma_f32_16x16x32_bf16(
            a[mi], b[ni], acc[mi][ni], 0, 0, 0);
    __builtin_amdgcn_s_setprio(0);
  }

  unsigned short* Yp = Y + (size_t)kh * NROWS * ND;
#pragma unroll
  for (int mi = 0; mi < 4; ++mi)
#pragma unroll
    for (int j = 0; j < 4; ++j) {
      int r = mt * 128 + wr * 64 + mi * 16 + l4 * 4 + j;
      if (r >= cnt) continue;
      size_t row = (size_t)(off_e + r);
#pragma unroll
      for (int ni = 0; ni < 8; ++ni) {
        int d = nt * 256 + wc * 128 + ni * 16 + l15;
        Yp[row * ND + d] = f2bf(acc[mi][ni][j]);
      }
    }
}

// -------- combine: out[t] = tw0*(y[r0,kh0]+y[r0,kh1]) + tw1*(...) -----------
__global__ void combine_kernel(const unsigned short* __restrict__ yc,
                               const float* __restrict__ tw,
                               const int* __restrict__ choice,
                               const int* __restrict__ posn,
                               const int* __restrict__ off,
                               float* __restrict__ out) {
  int t = blockIdx.x;
  int tid = threadIdx.x;   // 256: one float4 (4 elems) each
  int ch = choice[t];
  int pp = posn[t];
  int e0 = ch & 15, e1 = (ch >> 4) & 15;
  size_t r0 = (size_t)(off[e0] + (pp & 0xffff));
  size_t r1 = (size_t)(off[e1] + (pp >> 16));
  float w0 = tw[t * 2], w1 = tw[t * 2 + 1];
  const size_t P = (size_t)NROWS * ND;
  ushort4 a0 = ((const ushort4*)(yc + r0 * ND))[tid];
  ushort4 b0 = ((const ushort4*)(yc + P + r0 * ND))[tid];
  ushort4 a1 = ((const ushort4*)(yc + r1 * ND))[tid];
  ushort4 b1 = ((const ushort4*)(yc + P + r1 * ND))[tid];
  float4 o;
  o.x = w0 * (bf2f(a0.x) + bf2f(b0.x)) + w1 * (bf2f(a1.x) + bf2f(b1.x));
  o.y = w0 * (bf2f(a0.y) + bf2f(b0.y)) + w1 * (bf2f(a1.y) + bf2f(b1.y));
  o.z = w0 * (bf2f(a0.z) + bf2f(b0.z)) + w1 * (bf2f(a1.z) + bf2f(b1.z));
  o.w = w0 * (bf2f(a0.w) + bf2f(b0.w)) + w1 * (bf2f(a1.w) + bf2f(b1.w));
  ((float4*)(out + (size_t)t * ND))[tid] = o;
}

// ---------------- workspace layout (bytes) ----------------
// counts:  0          (64)
// off:     64         (64)
// choice:  128        (16384)     end 16512
// posn:    16512      (16384)     end 32896
// tw:      32896      (32768)     end 65664
// list:    65664      (131072)    end 196736
// hsb:     196736     (8388608)   end 8585344
// w1b:     8585344    (33554432)  end 42139776   <- w1b|v1b contiguous
// v1b:     42139776   (33554432)  end 75694208
// w2t:     75694208   (33554432)  end 109248640
// hcomp:   109248640  (33554432)  end 142803072   [NROWS][NF] bf16
// ycomp:   142803072  (33554432)  end 176357504   [2][NROWS][ND] bf16

extern "C" void kernel_launch(void* const* d_in, const int* in_sizes, int n_in,
                              void* d_out, int out_size, void* d_ws, size_t ws_size,
                              hipStream_t stream) {
  const float* hs = (const float*)d_in[0];
  const float* rk = (const float*)d_in[1];
  const float* w1 = (const float*)d_in[2];
  const float* v1 = (const float*)d_in[3];
  const float* w2 = (const float*)d_in[4];
  float* out = (float*)d_out;
  float* wout = out + (size_t)NTOK * ND;

  char* ws = (char*)d_ws;
  int* counts = (int*)(ws + 0);
  int* off = (int*)(ws + 64);
  int* choice = (int*)(ws + 128);
  int* posn = (int*)(ws + 16512);
  float* tw = (float*)(ws + 32896);
  int* list = (int*)(ws + 65664);
  unsigned short* hsb = (unsigned short*)(ws + 196736);
  unsigned short* w1b = (unsigned short*)(ws + 8585344);
  unsigned short* v1b = (unsigned short*)(ws + 42139776);
  unsigned short* w2t = (unsigned short*)(ws + 75694208);
  unsigned short* hcomp = (unsigned short*)(ws + 109248640);
  unsigned short* ycomp = (unsigned short*)(ws + 142803072);
  (void)v1b;

  // router (also converts hs -> bf16), then list/offset construction
  router_kernel<<<NTOK / 4, 64, 0, stream>>>(hs, rk, wout, tw, choice, hsb);
  build_lists<<<1, 1024, 0, stream>>>(choice, counts, off, list, posn);

  // weight conversions: w1+v1 in one launch (contiguous dst), vectorized transpose
  cvt_bf16_2<<<4096, 256, 0, stream>>>(w1, v1, w1b, (int)(EFD / 4));
  transpose_w2<<<dim3(ND / 64, NF / 64, NE), 256, 0, stream>>>(w2, w2t);

  // fused pass1+2: h = silu(X@w1^T) * (X@v1^T) -> compacted hcomp
  // grid = 8e x 32mt x 16nt = 4096 (nt fastest)
  gemm_fused<<<4096, 256, 0, stream>>>(counts, off, list, hsb, w1b, v1b, hcomp);

  // pass3: y = h @ w2t^T, BN=256, split-K=2, sequential streams
  // grid = 8e x 32mt x (4nt x 2kh) = 2048
  gemm_p3<<<2048, 256, 0, stream>>>(counts, off, hcomp, w2t, ycomp);

  // combine: one token per block, gathers compacted bf16 partial rows
  combine_kernel<<<NTOK, 256, 0, stream>>>(ycomp, tw, choice, posn, off, out);
}